// Round 1
// baseline (225.930 us; speedup 1.0000x reference)
//
#include <hip/hip_runtime.h>
#include <hip/hip_bf16.h>
#include <math.h>

// Problem constants (match reference)
#define GN      1024
#define GH      256
#define GW      256
#define GTILE   16
#define N_TW    (GW / GTILE)   // 16
#define N_TH    (GH / GTILE)   // 16
#define FXc     300.0f
#define FYc     300.0f
#define CXc     128.0f
#define CYc     128.0f
#define NEARc   0.1f
#define FARc    100.0f
#define T_TH    0.0001f
#define PSX     (1.0f / FXc)
#define PSY     (1.0f / FYc)
#define TLX     (-CXc / FXc)
#define TLY     (-CYc / FYc)
#define HALF_W  (GW * 0.5f / FXc)
#define HALF_H  (GH * 0.5f / FYc)

// ws layout: 10 SoA arrays of GN floats, in sorted (by-depth) order:
// 0: mx, 1: my, 2: ia, 3: ib, 4: ic, 5: aa (= sigmoid(alpha)*maskf),
// 6: r2 (= (radius*3)^2), 7: cr, 8: cg, 9: cb

__global__ __launch_bounds__(GN) void prep_kernel(
    const float* __restrict__ mean, const float* __restrict__ qvec,
    const float* __restrict__ lsv,  const float* __restrict__ color,
    const float* __restrict__ alpha, const float* __restrict__ c2w,
    float* __restrict__ ws)
{
    __shared__ float skey[GN];
    const int i = threadIdx.x;

    // camera
    float R[3][3], t[3];
#pragma unroll
    for (int r = 0; r < 3; ++r) {
        R[r][0] = c2w[r * 4 + 0];
        R[r][1] = c2w[r * 4 + 1];
        R[r][2] = c2w[r * 4 + 2];
        t[r]    = c2w[r * 4 + 3];
    }

    const float m0 = mean[i * 3 + 0] - t[0];
    const float m1 = mean[i * 3 + 1] - t[1];
    const float m2 = mean[i * 3 + 2] - t[2];
    // mean_cam = (mean - t) @ Rcw  -> mc[j] = sum_r m[r] * R[r][j]
    const float xc    = m0 * R[0][0] + m1 * R[1][0] + m2 * R[2][0];
    const float yc    = m0 * R[0][1] + m1 * R[1][1] + m2 * R[2][1];
    const float depth = m0 * R[0][2] + m1 * R[1][2] + m2 * R[2][2];

    const float zc = fmaxf(depth, 1e-6f);
    const float iz = 1.0f / zc;
    const float mx = xc * iz, my = yc * iz;

    // quaternion -> rotation
    float qw = qvec[i * 4 + 0], qx = qvec[i * 4 + 1];
    float qy = qvec[i * 4 + 2], qz = qvec[i * 4 + 3];
    const float qinv = 1.0f / sqrtf(qw * qw + qx * qx + qy * qy + qz * qz);
    qw *= qinv; qx *= qinv; qy *= qinv; qz *= qinv;
    float Rq[3][3];
    Rq[0][0] = 1.0f - 2.0f * (qy * qy + qz * qz);
    Rq[0][1] = 2.0f * (qx * qy - qw * qz);
    Rq[0][2] = 2.0f * (qx * qz + qw * qy);
    Rq[1][0] = 2.0f * (qx * qy + qw * qz);
    Rq[1][1] = 1.0f - 2.0f * (qx * qx + qz * qz);
    Rq[1][2] = 2.0f * (qy * qz - qw * qx);
    Rq[2][0] = 2.0f * (qx * qz - qw * qy);
    Rq[2][1] = 2.0f * (qy * qz + qw * qx);
    Rq[2][2] = 1.0f - 2.0f * (qx * qx + qy * qy);

    const float s0 = expf(lsv[i * 3 + 0]);
    const float s1 = expf(lsv[i * 3 + 1]);
    const float s2 = expf(lsv[i * 3 + 2]);
    const float v0 = s0 * s0, v1 = s1 * s1, v2 = s2 * s2;

    // cov3d[a][b] = sum_j Rq[a][j] * v[j] * Rq[b][j]
    float V[3][3];
#pragma unroll
    for (int a = 0; a < 3; ++a)
#pragma unroll
        for (int b = 0; b < 3; ++b)
            V[a][b] = Rq[a][0] * v0 * Rq[b][0] + Rq[a][1] * v1 * Rq[b][1] +
                      Rq[a][2] * v2 * Rq[b][2];

    // J (2x3)
    float J[2][3];
    J[0][0] = iz;   J[0][1] = 0.0f; J[0][2] = -xc * iz * iz;
    J[1][0] = 0.0f; J[1][1] = iz;   J[1][2] = -yc * iz * iz;

    // JW[r][k] = sum_j J[r][j] * R[k][j]   (J @ Rcw^T)
    float JW[2][3];
#pragma unroll
    for (int r = 0; r < 2; ++r)
#pragma unroll
        for (int k = 0; k < 3; ++k)
            JW[r][k] = J[r][0] * R[k][0] + J[r][1] * R[k][1] + J[r][2] * R[k][2];

    // cov = JW V JW^T
    float M[2][3];
#pragma unroll
    for (int r = 0; r < 2; ++r)
#pragma unroll
        for (int c = 0; c < 3; ++c)
            M[r][c] = JW[r][0] * V[0][c] + JW[r][1] * V[1][c] + JW[r][2] * V[2][c];
    const float cov00 = M[0][0] * JW[0][0] + M[0][1] * JW[0][1] + M[0][2] * JW[0][2];
    const float cov01 = M[0][0] * JW[1][0] + M[0][1] * JW[1][1] + M[0][2] * JW[1][2];
    const float cov10 = M[1][0] * JW[0][0] + M[1][1] * JW[0][1] + M[1][2] * JW[0][2];
    const float cov11 = M[1][0] * JW[1][0] + M[1][1] * JW[1][1] + M[1][2] * JW[1][2];

    const float c00 = cov00;
    const float c01 = 0.5f * (cov01 + cov10);
    const float c11 = cov11;

    const float mm  = 0.5f * (c00 + c11);
    const float det = c00 * c11 - c01 * c01;
    const float radius = sqrtf(mm + sqrtf(fmaxf(mm * mm - det, 0.0f)));

    const float r3d  = fmaxf(s0, fmaxf(s1, s2));
    const float marg = r3d * iz;
    const bool maskf = (depth > NEARc) && (depth < FARc) &&
                       (fabsf(mx) < HALF_W + marg) && (fabsf(my) < HALF_H + marg);

    const float detc = fmaxf(det, 1e-12f);
    const float ia =  c11 / detc;
    const float ib = -c01 / detc;
    const float ic =  c00 / detc;

    const float sg = 1.0f / (1.0f + expf(-alpha[i]));
    const float aa = maskf ? sg : 0.0f;
    const float rr = radius * 3.0f;   // TILE_CULL_R
    const float r2 = rr * rr;

    const float key = maskf ? depth : 1e10f;
    skey[i] = key;
    __syncthreads();

    // stable rank sort (ascending)
    int rank = 0;
    for (int j = 0; j < GN; ++j) {
        const float kj = skey[j];
        rank += (kj < key) || (kj == key && j < i);
    }

    ws[0 * GN + rank] = mx;
    ws[1 * GN + rank] = my;
    ws[2 * GN + rank] = ia;
    ws[3 * GN + rank] = ib;
    ws[4 * GN + rank] = ic;
    ws[5 * GN + rank] = aa;
    ws[6 * GN + rank] = r2;
    ws[7 * GN + rank] = color[i * 3 + 0];
    ws[8 * GN + rank] = color[i * 3 + 1];
    ws[9 * GN + rank] = color[i * 3 + 2];
}

__global__ __launch_bounds__(256) void render_kernel(
    const float* __restrict__ ws, float* __restrict__ out)
{
    __shared__ float sd[10 * GN];
    for (int idx = threadIdx.x; idx < 10 * GN; idx += 256)
        sd[idx] = ws[idx];
    __syncthreads();

    const float* __restrict__ smx = sd + 0 * GN;
    const float* __restrict__ smy = sd + 1 * GN;
    const float* __restrict__ sia = sd + 2 * GN;
    const float* __restrict__ sib = sd + 3 * GN;
    const float* __restrict__ sic = sd + 4 * GN;
    const float* __restrict__ saa = sd + 5 * GN;
    const float* __restrict__ sr2 = sd + 6 * GN;
    const float* __restrict__ scr = sd + 7 * GN;
    const float* __restrict__ scg = sd + 8 * GN;
    const float* __restrict__ scb = sd + 9 * GN;

    const int tx = threadIdx.x & 15;
    const int ty = threadIdx.x >> 4;
    const int wp = blockIdx.x * GTILE + tx;
    const int hp = blockIdx.y * GTILE + ty;

    const float px = TLX + ((float)wp + 0.5f) * PSX;
    const float py = TLY + ((float)hp + 0.5f) * PSY;

    // tile bounds (uniform per block)
    const float tx0 = TLX + (float)blockIdx.x * (GTILE * PSX);
    const float tx1 = tx0 + GTILE * PSX;
    const float ty0 = TLY + (float)blockIdx.y * (GTILE * PSY);
    const float ty1 = ty0 + GTILE * PSY;

    float T = 1.0f, cr = 0.0f, cg = 0.0f, cb = 0.0f;

    for (int s = 0; s < GN; ++s) {
        // exact early exit: T monotone non-increasing; once all pixels in the
        // tile are below threshold, all remaining weights are exactly 0
        if ((s & 127) == 0) {
            if (__syncthreads_and(T <= T_TH)) break;
        }
        const float aa = saa[s];
        const float gx = smx[s], gy = smy[s];
        const float dxt = fmaxf(fmaxf(tx0 - gx, gx - tx1), 0.0f);
        const float dyt = fmaxf(fmaxf(ty0 - gy, gy - ty1), 0.0f);
        // block-uniform skip (tile cull + frustum mask)
        if (aa == 0.0f || dxt * dxt + dyt * dyt > sr2[s]) continue;

        const float dx = px - gx, dy = py - gy;
        const float quad = sia[s] * dx * dx + 2.0f * sib[s] * dx * dy + sic[s] * dy * dy;
        const float G = expf(-0.5f * quad);
        const float w = aa * G;
        const float wt = (T > T_TH) ? T * w : 0.0f;
        cr += wt * scr[s];
        cg += wt * scg[s];
        cb += wt * scb[s];
        T *= (1.0f - w);
    }

    const int o = (hp * GW + wp) * 3;
    out[o + 0] = cr;
    out[o + 1] = cg;
    out[o + 2] = cb;
}

extern "C" void kernel_launch(void* const* d_in, const int* in_sizes, int n_in,
                              void* d_out, int out_size, void* d_ws, size_t ws_size,
                              hipStream_t stream) {
    const float* mean  = (const float*)d_in[0];
    const float* qvec  = (const float*)d_in[1];
    const float* lsv   = (const float*)d_in[2];
    const float* color = (const float*)d_in[3];
    const float* alpha = (const float*)d_in[4];
    const float* c2w   = (const float*)d_in[5];
    float* out = (float*)d_out;
    float* ws  = (float*)d_ws;

    hipLaunchKernelGGL(prep_kernel, dim3(1), dim3(GN), 0, stream,
                       mean, qvec, lsv, color, alpha, c2w, ws);
    hipLaunchKernelGGL(render_kernel, dim3(N_TW, N_TH), dim3(256), 0, stream,
                       ws, out);
}

// Round 2
// 52.111 us; speedup vs baseline: 4.3355x; 4.3355x over previous
//
#include <hip/hip_runtime.h>
#include <hip/hip_bf16.h>
#include <math.h>

// Problem constants (match reference)
#define GN      1024
#define GH      256
#define GW      256
#define GTILE   16
#define N_TW    (GW / GTILE)   // 16
#define N_TH    (GH / GTILE)   // 16
#define FXc     300.0f
#define FYc     300.0f
#define CXc     128.0f
#define CYc     128.0f
#define NEARc   0.1f
#define FARc    100.0f
#define T_TH    0.0001f
#define PSX     (1.0f / FXc)
#define PSY     (1.0f / FYc)
#define TLX     (-CXc / FXc)
#define TLY     (-CYc / FYc)
#define HALF_W  (GW * 0.5f / FXc)
#define HALF_H  (GH * 0.5f / FYc)

// ws layout (40 KB total, depth-sorted order):
//   A[GN] float4 : (mx, my, r2, aa)        -- cull record
//   B[GN] float4 : (ia, ib, ic, cr)        -- quad coeffs + red
//   C[GN] float2 : (cg, cb)

__global__ __launch_bounds__(GN) void prep_kernel(
    const float* __restrict__ mean, const float* __restrict__ qvec,
    const float* __restrict__ lsv,  const float* __restrict__ color,
    const float* __restrict__ alpha, const float* __restrict__ c2w,
    float* __restrict__ ws)
{
    __shared__ float4 skey4[GN / 4];
    float* skey = (float*)skey4;
    const int i = threadIdx.x;

    // camera
    float R[3][3], t[3];
#pragma unroll
    for (int r = 0; r < 3; ++r) {
        R[r][0] = c2w[r * 4 + 0];
        R[r][1] = c2w[r * 4 + 1];
        R[r][2] = c2w[r * 4 + 2];
        t[r]    = c2w[r * 4 + 3];
    }

    const float m0 = mean[i * 3 + 0] - t[0];
    const float m1 = mean[i * 3 + 1] - t[1];
    const float m2 = mean[i * 3 + 2] - t[2];
    const float xc    = m0 * R[0][0] + m1 * R[1][0] + m2 * R[2][0];
    const float yc    = m0 * R[0][1] + m1 * R[1][1] + m2 * R[2][1];
    const float depth = m0 * R[0][2] + m1 * R[1][2] + m2 * R[2][2];

    const float zc = fmaxf(depth, 1e-6f);
    const float iz = 1.0f / zc;
    const float mx = xc * iz, my = yc * iz;

    // quaternion -> rotation
    float qw = qvec[i * 4 + 0], qx = qvec[i * 4 + 1];
    float qy = qvec[i * 4 + 2], qz = qvec[i * 4 + 3];
    const float qinv = 1.0f / sqrtf(qw * qw + qx * qx + qy * qy + qz * qz);
    qw *= qinv; qx *= qinv; qy *= qinv; qz *= qinv;
    float Rq[3][3];
    Rq[0][0] = 1.0f - 2.0f * (qy * qy + qz * qz);
    Rq[0][1] = 2.0f * (qx * qy - qw * qz);
    Rq[0][2] = 2.0f * (qx * qz + qw * qy);
    Rq[1][0] = 2.0f * (qx * qy + qw * qz);
    Rq[1][1] = 1.0f - 2.0f * (qx * qx + qz * qz);
    Rq[1][2] = 2.0f * (qy * qz - qw * qx);
    Rq[2][0] = 2.0f * (qx * qz - qw * qy);
    Rq[2][1] = 2.0f * (qy * qz + qw * qx);
    Rq[2][2] = 1.0f - 2.0f * (qx * qx + qy * qy);

    const float s0 = expf(lsv[i * 3 + 0]);
    const float s1 = expf(lsv[i * 3 + 1]);
    const float s2 = expf(lsv[i * 3 + 2]);
    const float v0 = s0 * s0, v1 = s1 * s1, v2 = s2 * s2;

    float V[3][3];
#pragma unroll
    for (int a = 0; a < 3; ++a)
#pragma unroll
        for (int b = 0; b < 3; ++b)
            V[a][b] = Rq[a][0] * v0 * Rq[b][0] + Rq[a][1] * v1 * Rq[b][1] +
                      Rq[a][2] * v2 * Rq[b][2];

    float J[2][3];
    J[0][0] = iz;   J[0][1] = 0.0f; J[0][2] = -xc * iz * iz;
    J[1][0] = 0.0f; J[1][1] = iz;   J[1][2] = -yc * iz * iz;

    float JW[2][3];
#pragma unroll
    for (int r = 0; r < 2; ++r)
#pragma unroll
        for (int k = 0; k < 3; ++k)
            JW[r][k] = J[r][0] * R[k][0] + J[r][1] * R[k][1] + J[r][2] * R[k][2];

    float M[2][3];
#pragma unroll
    for (int r = 0; r < 2; ++r)
#pragma unroll
        for (int c = 0; c < 3; ++c)
            M[r][c] = JW[r][0] * V[0][c] + JW[r][1] * V[1][c] + JW[r][2] * V[2][c];
    const float cov00 = M[0][0] * JW[0][0] + M[0][1] * JW[0][1] + M[0][2] * JW[0][2];
    const float cov01 = M[0][0] * JW[1][0] + M[0][1] * JW[1][1] + M[0][2] * JW[1][2];
    const float cov10 = M[1][0] * JW[0][0] + M[1][1] * JW[0][1] + M[1][2] * JW[0][2];
    const float cov11 = M[1][0] * JW[1][0] + M[1][1] * JW[1][1] + M[1][2] * JW[1][2];

    const float c00 = cov00;
    const float c01 = 0.5f * (cov01 + cov10);
    const float c11 = cov11;

    const float mm  = 0.5f * (c00 + c11);
    const float det = c00 * c11 - c01 * c01;
    const float radius = sqrtf(mm + sqrtf(fmaxf(mm * mm - det, 0.0f)));

    const float r3d  = fmaxf(s0, fmaxf(s1, s2));
    const float marg = r3d * iz;
    const bool maskf = (depth > NEARc) && (depth < FARc) &&
                       (fabsf(mx) < HALF_W + marg) && (fabsf(my) < HALF_H + marg);

    const float detc = fmaxf(det, 1e-12f);
    const float ia =  c11 / detc;
    const float ib = -c01 / detc;
    const float ic =  c00 / detc;

    const float sg = 1.0f / (1.0f + expf(-alpha[i]));
    const float aa = maskf ? sg : 0.0f;
    const float rr = radius * 3.0f;   // TILE_CULL_R
    const float r2 = rr * rr;

    const float key = maskf ? depth : 1e10f;
    skey[i] = key;
    __syncthreads();

    // stable rank sort (ascending), float4-vectorized LDS reads
    int rank = 0;
    for (int j4 = 0; j4 < GN / 4; ++j4) {
        const float4 kk = skey4[j4];
        const int j = j4 * 4;
        rank += (kk.x < key) || (kk.x == key && (j + 0) < i);
        rank += (kk.y < key) || (kk.y == key && (j + 1) < i);
        rank += (kk.z < key) || (kk.z == key && (j + 2) < i);
        rank += (kk.w < key) || (kk.w == key && (j + 3) < i);
    }

    float4* A = (float4*)ws;
    float4* B = A + GN;
    float2* C = (float2*)(B + GN);
    A[rank] = make_float4(mx, my, r2, aa);
    B[rank] = make_float4(ia, ib, ic, color[i * 3 + 0]);
    C[rank] = make_float2(color[i * 3 + 1], color[i * 3 + 2]);
}

__global__ __launch_bounds__(256) void render_kernel(
    const float* __restrict__ ws, float* __restrict__ out)
{
    const float4* __restrict__ A = (const float4*)ws;
    const float4* __restrict__ B = A + GN;
    const float2* __restrict__ C = (const float2*)(B + GN);

    __shared__ int    slist[GN];
    __shared__ int    wcnt[4];
    __shared__ int    sbase;
    __shared__ float4 sA[256];
    __shared__ float4 sB[256];
    __shared__ float2 sC[256];

    const int tid  = threadIdx.x;
    const int lane = tid & 63;
    const int wv   = tid >> 6;

    // tile bounds (uniform per block)
    const float tx0 = TLX + (float)blockIdx.x * (GTILE * PSX);
    const float tx1 = tx0 + GTILE * PSX;
    const float ty0 = TLY + (float)blockIdx.y * (GTILE * PSY);
    const float ty1 = ty0 + GTILE * PSY;

    // preload all 4 cull records up-front (one latency)
    const float4 a0 = A[tid +   0];
    const float4 a1 = A[tid + 256];
    const float4 a2 = A[tid + 512];
    const float4 a3 = A[tid + 768];

    if (tid == 0) sbase = 0;

    // ---- Phase 1: order-preserving ballot compaction of overlapping gaussians
#pragma unroll
    for (int c = 0; c < 4; ++c) {
        const float4 a = (c == 0) ? a0 : (c == 1) ? a1 : (c == 2) ? a2 : a3;
        const int s = c * 256 + tid;
        const float dxt = fmaxf(fmaxf(tx0 - a.x, a.x - tx1), 0.0f);
        const float dyt = fmaxf(fmaxf(ty0 - a.y, a.y - ty1), 0.0f);
        const bool keep = (a.w > 0.0f) && (dxt * dxt + dyt * dyt <= a.z);
        const unsigned long long m = __ballot(keep);
        if (lane == 0) wcnt[wv] = __popcll(m);
        __syncthreads();   // wcnt visible (also sbase=0 on first pass)
        int off = sbase;
        for (int w2 = 0; w2 < wv; ++w2) off += wcnt[w2];
        const int pre = __popcll(m & ((1ull << lane) - 1ull));
        if (keep) slist[off + pre] = s;
        __syncthreads();   // slist writes done before sbase update
        if (tid == 0) sbase += wcnt[0] + wcnt[1] + wcnt[2] + wcnt[3];
        __syncthreads();   // sbase visible for next chunk / final read
    }
    const int n = sbase;

    // ---- Phase 2: composite the compacted, depth-ordered list
    const int tx = tid & 15;
    const int ty = tid >> 4;
    const int wp = blockIdx.x * GTILE + tx;
    const int hp = blockIdx.y * GTILE + ty;
    const float px = TLX + ((float)wp + 0.5f) * PSX;
    const float py = TLY + ((float)hp + 0.5f) * PSY;

    float T = 1.0f, cr = 0.0f, cg = 0.0f, cb = 0.0f;

    for (int base = 0; base < n; base += 256) {
        const int cnt = min(256, n - base);
        __syncthreads();
        if (tid < cnt) {
            const int s = slist[base + tid];
            sA[tid] = A[s];
            sB[tid] = B[s];
            sC[tid] = C[s];
        }
        __syncthreads();
        for (int k = 0; k < cnt; ++k) {
            const float4 a = sA[k];
            const float4 b = sB[k];
            const float2 cc = sC[k];
            const float dx = px - a.x, dy = py - a.y;
            const float quad = b.x * dx * dx + 2.0f * b.y * dx * dy + b.z * dy * dy;
            const float G = __expf(-0.5f * quad);
            const float w = a.w * G;
            const float wt = (T > T_TH) ? T * w : 0.0f;
            cr += wt * b.w;
            cg += wt * cc.x;
            cb += wt * cc.y;
            T *= (1.0f - w);
        }
    }

    const int o = (hp * GW + wp) * 3;
    out[o + 0] = cr;
    out[o + 1] = cg;
    out[o + 2] = cb;
}

extern "C" void kernel_launch(void* const* d_in, const int* in_sizes, int n_in,
                              void* d_out, int out_size, void* d_ws, size_t ws_size,
                              hipStream_t stream) {
    const float* mean  = (const float*)d_in[0];
    const float* qvec  = (const float*)d_in[1];
    const float* lsv   = (const float*)d_in[2];
    const float* color = (const float*)d_in[3];
    const float* alpha = (const float*)d_in[4];
    const float* c2w   = (const float*)d_in[5];
    float* out = (float*)d_out;
    float* ws  = (float*)d_ws;

    hipLaunchKernelGGL(prep_kernel, dim3(1), dim3(GN), 0, stream,
                       mean, qvec, lsv, color, alpha, c2w, ws);
    hipLaunchKernelGGL(render_kernel, dim3(N_TW, N_TH), dim3(256), 0, stream,
                       ws, out);
}

// Round 3
// 41.997 us; speedup vs baseline: 5.3796x; 1.2408x over previous
//
#include <hip/hip_runtime.h>
#include <hip/hip_bf16.h>
#include <math.h>

// Problem constants (match reference)
#define GN      1024
#define GH      256
#define GW      256
#define GTILE   16
#define N_TW    (GW / GTILE)   // 16
#define N_TH    (GH / GTILE)   // 16
#define FXc     300.0f
#define FYc     300.0f
#define CXc     128.0f
#define CYc     128.0f
#define NEARc   0.1f
#define FARc    100.0f
#define T_TH    0.0001f
#define PSX     (1.0f / FXc)
#define PSY     (1.0f / FYc)
#define TLX     (-CXc / FXc)
#define TLY     (-CYc / FYc)
#define HALF_W  (GW * 0.5f / FXc)
#define HALF_H  (GH * 0.5f / FYc)

// ws layout (84 KB total), float element offsets:
//   Au (unsorted float4[GN])  @ 0
//   Bu (unsorted float4[GN])  @ 4*GN
//   A  (sorted   float4[GN])  @ 8*GN
//   B  (sorted   float4[GN])  @ 12*GN
//   Cu (unsorted float2[GN])  @ 16*GN
//   C  (sorted   float2[GN])  @ 18*GN
//   key (float[GN])           @ 20*GN
#define OFF_AU  0
#define OFF_BU  (4 * GN)
#define OFF_A   (8 * GN)
#define OFF_B   (12 * GN)
#define OFF_CU  (16 * GN)
#define OFF_C   (18 * GN)
#define OFF_KEY (20 * GN)

// A record: (mx, my, r2, aa)   B record: (ia, ib, ic, cr)   C record: (cg, cb)

__global__ __launch_bounds__(256) void prep_math(
    const float* __restrict__ mean, const float* __restrict__ qvec,
    const float* __restrict__ lsv,  const float* __restrict__ color,
    const float* __restrict__ alpha, const float* __restrict__ c2w,
    float* __restrict__ ws)
{
    const int i = blockIdx.x * 256 + threadIdx.x;

    float R[3][3], t[3];
#pragma unroll
    for (int r = 0; r < 3; ++r) {
        R[r][0] = c2w[r * 4 + 0];
        R[r][1] = c2w[r * 4 + 1];
        R[r][2] = c2w[r * 4 + 2];
        t[r]    = c2w[r * 4 + 3];
    }

    const float m0 = mean[i * 3 + 0] - t[0];
    const float m1 = mean[i * 3 + 1] - t[1];
    const float m2 = mean[i * 3 + 2] - t[2];
    const float xc    = m0 * R[0][0] + m1 * R[1][0] + m2 * R[2][0];
    const float yc    = m0 * R[0][1] + m1 * R[1][1] + m2 * R[2][1];
    const float depth = m0 * R[0][2] + m1 * R[1][2] + m2 * R[2][2];

    const float zc = fmaxf(depth, 1e-6f);
    const float iz = 1.0f / zc;
    const float mx = xc * iz, my = yc * iz;

    float qw = qvec[i * 4 + 0], qx = qvec[i * 4 + 1];
    float qy = qvec[i * 4 + 2], qz = qvec[i * 4 + 3];
    const float qinv = 1.0f / sqrtf(qw * qw + qx * qx + qy * qy + qz * qz);
    qw *= qinv; qx *= qinv; qy *= qinv; qz *= qinv;
    float Rq[3][3];
    Rq[0][0] = 1.0f - 2.0f * (qy * qy + qz * qz);
    Rq[0][1] = 2.0f * (qx * qy - qw * qz);
    Rq[0][2] = 2.0f * (qx * qz + qw * qy);
    Rq[1][0] = 2.0f * (qx * qy + qw * qz);
    Rq[1][1] = 1.0f - 2.0f * (qx * qx + qz * qz);
    Rq[1][2] = 2.0f * (qy * qz - qw * qx);
    Rq[2][0] = 2.0f * (qx * qz - qw * qy);
    Rq[2][1] = 2.0f * (qy * qz + qw * qx);
    Rq[2][2] = 1.0f - 2.0f * (qx * qx + qy * qy);

    const float s0 = expf(lsv[i * 3 + 0]);
    const float s1 = expf(lsv[i * 3 + 1]);
    const float s2 = expf(lsv[i * 3 + 2]);
    const float v0 = s0 * s0, v1 = s1 * s1, v2 = s2 * s2;

    float V[3][3];
#pragma unroll
    for (int a = 0; a < 3; ++a)
#pragma unroll
        for (int b = 0; b < 3; ++b)
            V[a][b] = Rq[a][0] * v0 * Rq[b][0] + Rq[a][1] * v1 * Rq[b][1] +
                      Rq[a][2] * v2 * Rq[b][2];

    float J[2][3];
    J[0][0] = iz;   J[0][1] = 0.0f; J[0][2] = -xc * iz * iz;
    J[1][0] = 0.0f; J[1][1] = iz;   J[1][2] = -yc * iz * iz;

    float JW[2][3];
#pragma unroll
    for (int r = 0; r < 2; ++r)
#pragma unroll
        for (int k = 0; k < 3; ++k)
            JW[r][k] = J[r][0] * R[k][0] + J[r][1] * R[k][1] + J[r][2] * R[k][2];

    float M[2][3];
#pragma unroll
    for (int r = 0; r < 2; ++r)
#pragma unroll
        for (int c = 0; c < 3; ++c)
            M[r][c] = JW[r][0] * V[0][c] + JW[r][1] * V[1][c] + JW[r][2] * V[2][c];
    const float cov00 = M[0][0] * JW[0][0] + M[0][1] * JW[0][1] + M[0][2] * JW[0][2];
    const float cov01 = M[0][0] * JW[1][0] + M[0][1] * JW[1][1] + M[0][2] * JW[1][2];
    const float cov10 = M[1][0] * JW[0][0] + M[1][1] * JW[0][1] + M[1][2] * JW[0][2];
    const float cov11 = M[1][0] * JW[1][0] + M[1][1] * JW[1][1] + M[1][2] * JW[1][2];

    const float c00 = cov00;
    const float c01 = 0.5f * (cov01 + cov10);
    const float c11 = cov11;

    const float mm  = 0.5f * (c00 + c11);
    const float det = c00 * c11 - c01 * c01;
    const float radius = sqrtf(mm + sqrtf(fmaxf(mm * mm - det, 0.0f)));

    const float r3d  = fmaxf(s0, fmaxf(s1, s2));
    const float marg = r3d * iz;
    const bool maskf = (depth > NEARc) && (depth < FARc) &&
                       (fabsf(mx) < HALF_W + marg) && (fabsf(my) < HALF_H + marg);

    const float detc = fmaxf(det, 1e-12f);
    const float ia =  c11 / detc;
    const float ib = -c01 / detc;
    const float ic =  c00 / detc;

    const float sg = 1.0f / (1.0f + expf(-alpha[i]));
    const float aa = maskf ? sg : 0.0f;
    const float rr = radius * 3.0f;   // TILE_CULL_R
    const float r2 = rr * rr;

    ((float4*)(ws + OFF_AU))[i] = make_float4(mx, my, r2, aa);
    ((float4*)(ws + OFF_BU))[i] = make_float4(ia, ib, ic, color[i * 3 + 0]);
    ((float2*)(ws + OFF_CU))[i] = make_float2(color[i * 3 + 1], color[i * 3 + 2]);
    ws[OFF_KEY + i] = maskf ? depth : 1e10f;
}

// 8 blocks x 128 threads: each thread ranks one gaussian and scatters its record
__global__ __launch_bounds__(128) void sort_scatter(float* __restrict__ ws)
{
    __shared__ float4 skey4[GN / 4];
    const int tid = threadIdx.x;
    const int i   = blockIdx.x * 128 + tid;

    // stage all keys (4 KB) into LDS: 128 threads x 2 float4
    const float4* __restrict__ kg = (const float4*)(ws + OFF_KEY);
    skey4[tid]       = kg[tid];
    skey4[tid + 128] = kg[tid + 128];
    __syncthreads();

    const float key = ((const float*)skey4)[i];

    int rank = 0;
#pragma unroll 4
    for (int j4 = 0; j4 < GN / 4; ++j4) {
        const float4 kk = skey4[j4];     // broadcast read: conflict-free
        const int j = j4 * 4;
        rank += (kk.x < key) || (kk.x == key && (j + 0) < i);
        rank += (kk.y < key) || (kk.y == key && (j + 1) < i);
        rank += (kk.z < key) || (kk.z == key && (j + 2) < i);
        rank += (kk.w < key) || (kk.w == key && (j + 3) < i);
    }

    ((float4*)(ws + OFF_A))[rank] = ((const float4*)(ws + OFF_AU))[i];
    ((float4*)(ws + OFF_B))[rank] = ((const float4*)(ws + OFF_BU))[i];
    ((float2*)(ws + OFF_C))[rank] = ((const float2*)(ws + OFF_CU))[i];
}

__global__ __launch_bounds__(256) void render_kernel(
    const float* __restrict__ ws, float* __restrict__ out)
{
    const float4* __restrict__ A = (const float4*)(ws + OFF_A);
    const float4* __restrict__ B = (const float4*)(ws + OFF_B);
    const float2* __restrict__ C = (const float2*)(ws + OFF_C);

    __shared__ int    slist[GN];
    __shared__ int    wcnt[4];
    __shared__ int    sbase;
    __shared__ float4 sA[256];
    __shared__ float4 sB[256];
    __shared__ float2 sC[256];

    const int tid  = threadIdx.x;
    const int lane = tid & 63;
    const int wv   = tid >> 6;

    const float tx0 = TLX + (float)blockIdx.x * (GTILE * PSX);
    const float tx1 = tx0 + GTILE * PSX;
    const float ty0 = TLY + (float)blockIdx.y * (GTILE * PSY);
    const float ty1 = ty0 + GTILE * PSY;

    const float4 a0 = A[tid +   0];
    const float4 a1 = A[tid + 256];
    const float4 a2 = A[tid + 512];
    const float4 a3 = A[tid + 768];

    if (tid == 0) sbase = 0;

    // ---- Phase 1: order-preserving ballot compaction of overlapping gaussians
#pragma unroll
    for (int c = 0; c < 4; ++c) {
        const float4 a = (c == 0) ? a0 : (c == 1) ? a1 : (c == 2) ? a2 : a3;
        const int s = c * 256 + tid;
        const float dxt = fmaxf(fmaxf(tx0 - a.x, a.x - tx1), 0.0f);
        const float dyt = fmaxf(fmaxf(ty0 - a.y, a.y - ty1), 0.0f);
        const bool keep = (a.w > 0.0f) && (dxt * dxt + dyt * dyt <= a.z);
        const unsigned long long m = __ballot(keep);
        if (lane == 0) wcnt[wv] = __popcll(m);
        __syncthreads();
        int off = sbase;
        for (int w2 = 0; w2 < wv; ++w2) off += wcnt[w2];
        const int pre = __popcll(m & ((1ull << lane) - 1ull));
        if (keep) slist[off + pre] = s;
        __syncthreads();
        if (tid == 0) sbase += wcnt[0] + wcnt[1] + wcnt[2] + wcnt[3];
        __syncthreads();
    }
    const int n = sbase;

    // ---- Phase 2: composite the compacted, depth-ordered list
    const int tx = tid & 15;
    const int ty = tid >> 4;
    const int wp = blockIdx.x * GTILE + tx;
    const int hp = blockIdx.y * GTILE + ty;
    const float px = TLX + ((float)wp + 0.5f) * PSX;
    const float py = TLY + ((float)hp + 0.5f) * PSY;

    float T = 1.0f, cr = 0.0f, cg = 0.0f, cb = 0.0f;

    for (int base = 0; base < n; base += 256) {
        const int cnt = min(256, n - base);
        __syncthreads();
        if (tid < cnt) {
            const int s = slist[base + tid];
            sA[tid] = A[s];
            sB[tid] = B[s];
            sC[tid] = C[s];
        }
        __syncthreads();
        for (int k = 0; k < cnt; ++k) {
            const float4 a = sA[k];
            const float4 b = sB[k];
            const float2 cc = sC[k];
            const float dx = px - a.x, dy = py - a.y;
            const float quad = b.x * dx * dx + 2.0f * b.y * dx * dy + b.z * dy * dy;
            const float G = __expf(-0.5f * quad);
            const float w = a.w * G;
            const float wt = (T > T_TH) ? T * w : 0.0f;
            cr += wt * b.w;
            cg += wt * cc.x;
            cb += wt * cc.y;
            T *= (1.0f - w);
        }
    }

    const int o = (hp * GW + wp) * 3;
    out[o + 0] = cr;
    out[o + 1] = cg;
    out[o + 2] = cb;
}

extern "C" void kernel_launch(void* const* d_in, const int* in_sizes, int n_in,
                              void* d_out, int out_size, void* d_ws, size_t ws_size,
                              hipStream_t stream) {
    const float* mean  = (const float*)d_in[0];
    const float* qvec  = (const float*)d_in[1];
    const float* lsv   = (const float*)d_in[2];
    const float* color = (const float*)d_in[3];
    const float* alpha = (const float*)d_in[4];
    const float* c2w   = (const float*)d_in[5];
    float* out = (float*)d_out;
    float* ws  = (float*)d_ws;

    hipLaunchKernelGGL(prep_math, dim3(4), dim3(256), 0, stream,
                       mean, qvec, lsv, color, alpha, c2w, ws);
    hipLaunchKernelGGL(sort_scatter, dim3(8), dim3(128), 0, stream, ws);
    hipLaunchKernelGGL(render_kernel, dim3(N_TW, N_TH), dim3(256), 0, stream,
                       ws, out);
}

// Round 4
// 16.385 us; speedup vs baseline: 13.7890x; 2.5632x over previous
//
#include <hip/hip_runtime.h>
#include <hip/hip_bf16.h>
#include <math.h>

// Problem constants (match reference)
#define GN      1024
#define GH      256
#define GW      256
#define GTILE   16
#define N_TW    (GW / GTILE)   // 16
#define N_TH    (GH / GTILE)   // 16
#define FXc     300.0f
#define FYc     300.0f
#define CXc     128.0f
#define CYc     128.0f
#define NEARc   0.1f
#define FARc    100.0f
#define T_TH    0.0001f
#define PSX     (1.0f / FXc)
#define PSY     (1.0f / FYc)
#define TLX     (-CXc / FXc)
#define TLY     (-CYc / FYc)
#define HALF_W  (GW * 0.5f / FXc)
#define HALF_H  (GH * 0.5f / FYc)

// Single fused kernel: one block per 16x16 tile. Each block redundantly
// computes per-gaussian math for all GN gaussians (cheap: ~300 FLOP each),
// ballot-compacts the ones overlapping its tile (order-preserving -> original
// index order), rank-sorts that short list by (depth, index) in LDS (equal to
// the global stable argsort restricted to the kept subset; excluded gaussians
// have w==0 for this tile, so compositing is exact), then composites.
__global__ __launch_bounds__(256) void splat_all(
    const float* __restrict__ mean, const float* __restrict__ qvec,
    const float* __restrict__ lsv,  const float* __restrict__ color,
    const float* __restrict__ alpha, const float* __restrict__ c2w,
    float* __restrict__ out)
{
    __shared__ float  skey[GN];   // depth keys, compacted
    __shared__ float4 sP0[GN];    // (mx, my, ia, ib)
    __shared__ float4 sP1[GN];    // (ic, aa, cr, cg)
    __shared__ float  sP2[GN];    // cb
    __shared__ int    sord[GN];   // sorted order -> compact index
    __shared__ int    wcnt[4];
    __shared__ int    sbase;

    const int tid  = threadIdx.x;
    const int lane = tid & 63;
    const int wv   = tid >> 6;

    // camera (uniform scalar loads)
    float R[3][3], t[3];
#pragma unroll
    for (int r = 0; r < 3; ++r) {
        R[r][0] = c2w[r * 4 + 0];
        R[r][1] = c2w[r * 4 + 1];
        R[r][2] = c2w[r * 4 + 2];
        t[r]    = c2w[r * 4 + 3];
    }

    // tile bounds (uniform per block)
    const float tx0 = TLX + (float)blockIdx.x * (GTILE * PSX);
    const float tx1 = tx0 + GTILE * PSX;
    const float ty0 = TLY + (float)blockIdx.y * (GTILE * PSY);
    const float ty1 = ty0 + GTILE * PSY;

    if (tid == 0) sbase = 0;

    // ---- Phase A: per-gaussian math + order-preserving ballot compaction
#pragma unroll 1
    for (int c = 0; c < 4; ++c) {
        const int i = c * 256 + tid;

        const float m0 = mean[i * 3 + 0] - t[0];
        const float m1 = mean[i * 3 + 1] - t[1];
        const float m2 = mean[i * 3 + 2] - t[2];
        const float xc    = m0 * R[0][0] + m1 * R[1][0] + m2 * R[2][0];
        const float yc    = m0 * R[0][1] + m1 * R[1][1] + m2 * R[2][1];
        const float depth = m0 * R[0][2] + m1 * R[1][2] + m2 * R[2][2];

        const float zc = fmaxf(depth, 1e-6f);
        const float iz = 1.0f / zc;
        const float mx = xc * iz, my = yc * iz;

        float qw = qvec[i * 4 + 0], qx = qvec[i * 4 + 1];
        float qy = qvec[i * 4 + 2], qz = qvec[i * 4 + 3];
        const float qinv = 1.0f / sqrtf(qw * qw + qx * qx + qy * qy + qz * qz);
        qw *= qinv; qx *= qinv; qy *= qinv; qz *= qinv;
        float Rq[3][3];
        Rq[0][0] = 1.0f - 2.0f * (qy * qy + qz * qz);
        Rq[0][1] = 2.0f * (qx * qy - qw * qz);
        Rq[0][2] = 2.0f * (qx * qz + qw * qy);
        Rq[1][0] = 2.0f * (qx * qy + qw * qz);
        Rq[1][1] = 1.0f - 2.0f * (qx * qx + qz * qz);
        Rq[1][2] = 2.0f * (qy * qz - qw * qx);
        Rq[2][0] = 2.0f * (qx * qz - qw * qy);
        Rq[2][1] = 2.0f * (qy * qz + qw * qx);
        Rq[2][2] = 1.0f - 2.0f * (qx * qx + qy * qy);

        const float s0 = expf(lsv[i * 3 + 0]);
        const float s1 = expf(lsv[i * 3 + 1]);
        const float s2 = expf(lsv[i * 3 + 2]);
        const float v0 = s0 * s0, v1 = s1 * s1, v2 = s2 * s2;

        float V[3][3];
#pragma unroll
        for (int a = 0; a < 3; ++a)
#pragma unroll
            for (int b = 0; b < 3; ++b)
                V[a][b] = Rq[a][0] * v0 * Rq[b][0] + Rq[a][1] * v1 * Rq[b][1] +
                          Rq[a][2] * v2 * Rq[b][2];

        float J[2][3];
        J[0][0] = iz;   J[0][1] = 0.0f; J[0][2] = -xc * iz * iz;
        J[1][0] = 0.0f; J[1][1] = iz;   J[1][2] = -yc * iz * iz;

        float JW[2][3];
#pragma unroll
        for (int r = 0; r < 2; ++r)
#pragma unroll
            for (int k = 0; k < 3; ++k)
                JW[r][k] = J[r][0] * R[k][0] + J[r][1] * R[k][1] + J[r][2] * R[k][2];

        float M[2][3];
#pragma unroll
        for (int r = 0; r < 2; ++r)
#pragma unroll
            for (int cc = 0; cc < 3; ++cc)
                M[r][cc] = JW[r][0] * V[0][cc] + JW[r][1] * V[1][cc] + JW[r][2] * V[2][cc];
        const float cov00 = M[0][0] * JW[0][0] + M[0][1] * JW[0][1] + M[0][2] * JW[0][2];
        const float cov01 = M[0][0] * JW[1][0] + M[0][1] * JW[1][1] + M[0][2] * JW[1][2];
        const float cov10 = M[1][0] * JW[0][0] + M[1][1] * JW[0][1] + M[1][2] * JW[0][2];
        const float cov11 = M[1][0] * JW[1][0] + M[1][1] * JW[1][1] + M[1][2] * JW[1][2];

        const float c00 = cov00;
        const float c01 = 0.5f * (cov01 + cov10);
        const float c11 = cov11;

        const float mm  = 0.5f * (c00 + c11);
        const float det = c00 * c11 - c01 * c01;
        const float radius = sqrtf(mm + sqrtf(fmaxf(mm * mm - det, 0.0f)));

        const float r3d  = fmaxf(s0, fmaxf(s1, s2));
        const float marg = r3d * iz;
        const bool maskf = (depth > NEARc) && (depth < FARc) &&
                           (fabsf(mx) < HALF_W + marg) && (fabsf(my) < HALF_H + marg);

        const float detc = fmaxf(det, 1e-12f);
        const float ia =  c11 / detc;
        const float ib = -c01 / detc;
        const float ic =  c00 / detc;

        const float sg = 1.0f / (1.0f + expf(-alpha[i]));
        const float aa = maskf ? sg : 0.0f;
        const float rr = radius * 3.0f;   // TILE_CULL_R
        const float r2 = rr * rr;

        // tile cull
        const float dxt = fmaxf(fmaxf(tx0 - mx, mx - tx1), 0.0f);
        const float dyt = fmaxf(fmaxf(ty0 - my, my - ty1), 0.0f);
        const bool keep = (aa > 0.0f) && (dxt * dxt + dyt * dyt <= r2);

        const unsigned long long bm = __ballot(keep);
        if (lane == 0) wcnt[wv] = __popcll(bm);
        __syncthreads();   // wcnt (and sbase on first pass) visible
        int off = sbase;
        for (int w2 = 0; w2 < wv; ++w2) off += wcnt[w2];
        const int pre = __popcll(bm & ((1ull << lane) - 1ull));
        if (keep) {
            const int p = off + pre;
            skey[p] = depth;
            sP0[p]  = make_float4(mx, my, ia, ib);
            sP1[p]  = make_float4(ic, aa, color[i * 3 + 0], color[i * 3 + 1]);
            sP2[p]  = color[i * 3 + 2];
        }
        __syncthreads();   // payload writes done before sbase update
        if (tid == 0) sbase += wcnt[0] + wcnt[1] + wcnt[2] + wcnt[3];
        __syncthreads();   // sbase visible
    }
    const int n = sbase;

    // ---- Phase B: rank-sort the short list by (depth, compact index)
    // compaction preserved original-index order, so j<t in compact order
    // == j<i in original order -> matches global stable argsort semantics
    for (int tt = tid; tt < n; tt += 256) {
        const float k = skey[tt];
        int rank = 0;
        for (int j = 0; j < n; ++j) {
            const float kj = skey[j];
            rank += (kj < k) || (kj == k && j < tt);
        }
        sord[rank] = tt;
    }
    __syncthreads();

    // ---- Phase C: composite front-to-back
    const int tx = tid & 15;
    const int ty = tid >> 4;
    const int wp = blockIdx.x * GTILE + tx;
    const int hp = blockIdx.y * GTILE + ty;
    const float px = TLX + ((float)wp + 0.5f) * PSX;
    const float py = TLY + ((float)hp + 0.5f) * PSY;

    float T = 1.0f, cr = 0.0f, cg = 0.0f, cb = 0.0f;

    for (int s = 0; s < n; ++s) {
        if ((s & 63) == 0) {
            if (__syncthreads_and(T <= T_TH)) break;   // exact: T monotone
        }
        const int p = sord[s];
        const float4 p0 = sP0[p];     // broadcast reads: conflict-free
        const float4 p1 = sP1[p];
        const float cbv = sP2[p];
        const float dx = px - p0.x, dy = py - p0.y;
        const float quad = p0.z * dx * dx + 2.0f * p0.w * dx * dy + p1.x * dy * dy;
        const float G = __expf(-0.5f * quad);
        const float w = p1.y * G;
        const float wt = (T > T_TH) ? T * w : 0.0f;
        cr += wt * p1.z;
        cg += wt * p1.w;
        cb += wt * cbv;
        T *= (1.0f - w);
    }

    const int o = (hp * GW + wp) * 3;
    out[o + 0] = cr;
    out[o + 1] = cg;
    out[o + 2] = cb;
}

extern "C" void kernel_launch(void* const* d_in, const int* in_sizes, int n_in,
                              void* d_out, int out_size, void* d_ws, size_t ws_size,
                              hipStream_t stream) {
    const float* mean  = (const float*)d_in[0];
    const float* qvec  = (const float*)d_in[1];
    const float* lsv   = (const float*)d_in[2];
    const float* color = (const float*)d_in[3];
    const float* alpha = (const float*)d_in[4];
    const float* c2w   = (const float*)d_in[5];
    float* out = (float*)d_out;

    hipLaunchKernelGGL(splat_all, dim3(N_TW, N_TH), dim3(256), 0, stream,
                       mean, qvec, lsv, color, alpha, c2w, out);
}

// Round 5
// 14.493 us; speedup vs baseline: 15.5890x; 1.1305x over previous
//
#include <hip/hip_runtime.h>
#include <hip/hip_bf16.h>
#include <math.h>

// Problem constants (match reference)
#define GN      1024
#define GH      256
#define GW      256
#define GTILE   16
#define N_TW    (GW / GTILE)   // 16
#define N_TH    (GH / GTILE)   // 16
#define FXc     300.0f
#define FYc     300.0f
#define CXc     128.0f
#define CYc     128.0f
#define NEARc   0.1f
#define FARc    100.0f
#define T_TH    0.0001f
#define PSX     (1.0f / FXc)
#define PSY     (1.0f / FYc)
#define TLX     (-CXc / FXc)
#define TLY     (-CYc / FYc)
#define HALF_W  (GW * 0.5f / FXc)
#define HALF_H  (GH * 0.5f / FYc)

// One block per 16x16 tile. Each block redundantly computes per-gaussian math
// for all GN gaussians with all loads+math hoisted before any barrier (ILP
// latency hiding at 1 wave/SIMD), then a 2-barrier order-preserving ballot
// compaction, a local rank-sort by (depth, original index), and front-to-back
// compositing. Exactness: excluded gaussians have w==0 for this tile; local
// stable sort == global stable argsort restricted to the kept subset.
__global__ __launch_bounds__(256) void splat_all(
    const float* __restrict__ mean, const float* __restrict__ qvec,
    const float* __restrict__ lsv,  const float* __restrict__ color,
    const float* __restrict__ alpha, const float* __restrict__ c2w,
    float* __restrict__ out)
{
    __shared__ float  skey[GN];   // depth keys, compacted
    __shared__ float4 sP0[GN];    // (mx, my, ia, ib)
    __shared__ float4 sP1[GN];    // (ic, aa, cr, cg)
    __shared__ float  sP2[GN];    // cb
    __shared__ int    sord[GN];   // sorted order -> compact index
    __shared__ int    scnt[16];   // [chunk][wave] keep counts

    const int tid  = threadIdx.x;
    const int lane = tid & 63;
    const int wv   = tid >> 6;

    // camera (uniform scalar loads)
    float R[3][3], t[3];
#pragma unroll
    for (int r = 0; r < 3; ++r) {
        R[r][0] = c2w[r * 4 + 0];
        R[r][1] = c2w[r * 4 + 1];
        R[r][2] = c2w[r * 4 + 2];
        t[r]    = c2w[r * 4 + 3];
    }

    // tile bounds (uniform per block)
    const float tx0 = TLX + (float)blockIdx.x * (GTILE * PSX);
    const float tx1 = tx0 + GTILE * PSX;
    const float ty0 = TLY + (float)blockIdx.y * (GTILE * PSY);
    const float ty1 = ty0 + GTILE * PSY;

    // ---- Phase A1: math for all 4 chunks, no barriers (loads all in flight)
    float r_dep[4], r_mx[4], r_my[4], r_ia[4], r_ib[4], r_ic[4], r_aa[4];
    float r_cr[4], r_cg[4], r_cb[4];
    bool  r_keep[4];

#pragma unroll
    for (int c = 0; c < 4; ++c) {
        const int i = c * 256 + tid;

        const float m0 = mean[i * 3 + 0] - t[0];
        const float m1 = mean[i * 3 + 1] - t[1];
        const float m2 = mean[i * 3 + 2] - t[2];
        const float4 q4 = ((const float4*)qvec)[i];
        const float l0 = lsv[i * 3 + 0];
        const float l1 = lsv[i * 3 + 1];
        const float l2 = lsv[i * 3 + 2];
        const float al = alpha[i];
        r_cr[c] = color[i * 3 + 0];
        r_cg[c] = color[i * 3 + 1];
        r_cb[c] = color[i * 3 + 2];

        const float xc    = m0 * R[0][0] + m1 * R[1][0] + m2 * R[2][0];
        const float yc    = m0 * R[0][1] + m1 * R[1][1] + m2 * R[2][1];
        const float depth = m0 * R[0][2] + m1 * R[1][2] + m2 * R[2][2];

        const float zc = fmaxf(depth, 1e-6f);
        const float iz = 1.0f / zc;
        const float mx = xc * iz, my = yc * iz;

        float qw = q4.x, qx = q4.y, qy = q4.z, qz = q4.w;
        const float qinv = 1.0f / sqrtf(qw * qw + qx * qx + qy * qy + qz * qz);
        qw *= qinv; qx *= qinv; qy *= qinv; qz *= qinv;
        float Rq[3][3];
        Rq[0][0] = 1.0f - 2.0f * (qy * qy + qz * qz);
        Rq[0][1] = 2.0f * (qx * qy - qw * qz);
        Rq[0][2] = 2.0f * (qx * qz + qw * qy);
        Rq[1][0] = 2.0f * (qx * qy + qw * qz);
        Rq[1][1] = 1.0f - 2.0f * (qx * qx + qz * qz);
        Rq[1][2] = 2.0f * (qy * qz - qw * qx);
        Rq[2][0] = 2.0f * (qx * qz - qw * qy);
        Rq[2][1] = 2.0f * (qy * qz + qw * qx);
        Rq[2][2] = 1.0f - 2.0f * (qx * qx + qy * qy);

        const float s0 = __expf(l0);
        const float s1 = __expf(l1);
        const float s2 = __expf(l2);
        const float v0 = s0 * s0, v1 = s1 * s1, v2 = s2 * s2;

        float V[3][3];
#pragma unroll
        for (int a = 0; a < 3; ++a)
#pragma unroll
            for (int b = 0; b < 3; ++b)
                V[a][b] = Rq[a][0] * v0 * Rq[b][0] + Rq[a][1] * v1 * Rq[b][1] +
                          Rq[a][2] * v2 * Rq[b][2];

        float J[2][3];
        J[0][0] = iz;   J[0][1] = 0.0f; J[0][2] = -xc * iz * iz;
        J[1][0] = 0.0f; J[1][1] = iz;   J[1][2] = -yc * iz * iz;

        float JW[2][3];
#pragma unroll
        for (int r = 0; r < 2; ++r)
#pragma unroll
            for (int k = 0; k < 3; ++k)
                JW[r][k] = J[r][0] * R[k][0] + J[r][1] * R[k][1] + J[r][2] * R[k][2];

        float M[2][3];
#pragma unroll
        for (int r = 0; r < 2; ++r)
#pragma unroll
            for (int cc = 0; cc < 3; ++cc)
                M[r][cc] = JW[r][0] * V[0][cc] + JW[r][1] * V[1][cc] + JW[r][2] * V[2][cc];
        const float cov00 = M[0][0] * JW[0][0] + M[0][1] * JW[0][1] + M[0][2] * JW[0][2];
        const float cov01 = M[0][0] * JW[1][0] + M[0][1] * JW[1][1] + M[0][2] * JW[1][2];
        const float cov10 = M[1][0] * JW[0][0] + M[1][1] * JW[0][1] + M[1][2] * JW[0][2];
        const float cov11 = M[1][0] * JW[1][0] + M[1][1] * JW[1][1] + M[1][2] * JW[1][2];

        const float c00 = cov00;
        const float c01 = 0.5f * (cov01 + cov10);
        const float c11 = cov11;

        const float mm  = 0.5f * (c00 + c11);
        const float det = c00 * c11 - c01 * c01;
        const float radius = sqrtf(mm + sqrtf(fmaxf(mm * mm - det, 0.0f)));

        const float r3d  = fmaxf(s0, fmaxf(s1, s2));
        const float marg = r3d * iz;
        const bool maskf = (depth > NEARc) && (depth < FARc) &&
                           (fabsf(mx) < HALF_W + marg) && (fabsf(my) < HALF_H + marg);

        const float detc = fmaxf(det, 1e-12f);
        const float ia =  c11 / detc;
        const float ib = -c01 / detc;
        const float ic =  c00 / detc;

        const float sg = 1.0f / (1.0f + __expf(-al));
        const float aa = maskf ? sg : 0.0f;
        const float rr = radius * 3.0f;   // TILE_CULL_R
        const float r2 = rr * rr;

        const float dxt = fmaxf(fmaxf(tx0 - mx, mx - tx1), 0.0f);
        const float dyt = fmaxf(fmaxf(ty0 - my, my - ty1), 0.0f);

        r_dep[c] = depth; r_mx[c] = mx; r_my[c] = my;
        r_ia[c] = ia; r_ib[c] = ib; r_ic[c] = ic; r_aa[c] = aa;
        r_keep[c] = (aa > 0.0f) && (dxt * dxt + dyt * dyt <= r2);
    }

    // ---- Phase A2: single-pass order-preserving compaction (2 barriers)
    unsigned long long bm[4];
#pragma unroll
    for (int c = 0; c < 4; ++c) {
        bm[c] = __ballot(r_keep[c]);
        if (lane == 0) scnt[c * 4 + wv] = __popcll(bm[c]);
    }
    __syncthreads();

    int cnt[16];
#pragma unroll
    for (int k = 0; k < 16; ++k) cnt[k] = scnt[k];   // broadcast reads
    int chunkbase[5];
    chunkbase[0] = 0;
#pragma unroll
    for (int c = 0; c < 4; ++c)
        chunkbase[c + 1] = chunkbase[c] + cnt[c * 4 + 0] + cnt[c * 4 + 1] +
                           cnt[c * 4 + 2] + cnt[c * 4 + 3];
    const int n = chunkbase[4];

    const unsigned long long lmask = (lane == 63) ? ~0ull >> 1 : (1ull << lane) - 1ull;
#pragma unroll
    for (int c = 0; c < 4; ++c) {
        if (r_keep[c]) {
            int off = chunkbase[c];
            for (int w2 = 0; w2 < wv; ++w2) off += cnt[c * 4 + w2];
            off += __popcll(bm[c] & ((1ull << lane) - 1ull));
            skey[off] = r_dep[c];
            sP0[off]  = make_float4(r_mx[c], r_my[c], r_ia[c], r_ib[c]);
            sP1[off]  = make_float4(r_ic[c], r_aa[c], r_cr[c], r_cg[c]);
            sP2[off]  = r_cb[c];
        }
    }
    __syncthreads();

    // ---- Phase B: rank-sort the short list by (depth, compact index)
    for (int tt = tid; tt < n; tt += 256) {
        const float k = skey[tt];
        int rank = 0;
        for (int j = 0; j < n; ++j) {
            const float kj = skey[j];
            rank += (kj < k) || (kj == k && j < tt);
        }
        sord[rank] = tt;
    }
    __syncthreads();

    // ---- Phase C: composite front-to-back
    const int tx = tid & 15;
    const int ty = tid >> 4;
    const int wp = blockIdx.x * GTILE + tx;
    const int hp = blockIdx.y * GTILE + ty;
    const float px = TLX + ((float)wp + 0.5f) * PSX;
    const float py = TLY + ((float)hp + 0.5f) * PSY;

    float T = 1.0f, cr = 0.0f, cg = 0.0f, cb = 0.0f;

    for (int s = 0; s < n; ++s) {
        if ((s & 63) == 0) {
            if (__syncthreads_and(T <= T_TH)) break;   // exact: T monotone
        }
        const int p = sord[s];
        const float4 p0 = sP0[p];     // broadcast reads: conflict-free
        const float4 p1 = sP1[p];
        const float cbv = sP2[p];
        const float dx = px - p0.x, dy = py - p0.y;
        const float quad = p0.z * dx * dx + 2.0f * p0.w * dx * dy + p1.x * dy * dy;
        const float G = __expf(-0.5f * quad);
        const float w = p1.y * G;
        const float wt = (T > T_TH) ? T * w : 0.0f;
        cr += wt * p1.z;
        cg += wt * p1.w;
        cb += wt * cbv;
        T *= (1.0f - w);
    }

    const int o = (hp * GW + wp) * 3;
    out[o + 0] = cr;
    out[o + 1] = cg;
    out[o + 2] = cb;
}

extern "C" void kernel_launch(void* const* d_in, const int* in_sizes, int n_in,
                              void* d_out, int out_size, void* d_ws, size_t ws_size,
                              hipStream_t stream) {
    const float* mean  = (const float*)d_in[0];
    const float* qvec  = (const float*)d_in[1];
    const float* lsv   = (const float*)d_in[2];
    const float* color = (const float*)d_in[3];
    const float* alpha = (const float*)d_in[4];
    const float* c2w   = (const float*)d_in[5];
    float* out = (float*)d_out;

    hipLaunchKernelGGL(splat_all, dim3(N_TW, N_TH), dim3(256), 0, stream,
                       mean, qvec, lsv, color, alpha, c2w, out);
}